// Round 1
// baseline (716.821 us; speedup 1.0000x reference)
//
#include <hip/hip_runtime.h>

// AvgPool2d k=3 s=2 VALID. x: (8,64,512,512) fp32 -> out: (8,64,255,255) fp32.
//
// Dense-load / rolling-accumulator design:
//  - One wave covers a full 512-wide input row with two 100%-dense float4
//    loads: lane i reads cols 4i..4i+3 and 256+4i..256+4i+3 (byte 16*i —
//    every cache line fully consumed by a single instruction).
//  - Window-overlap column (4i+4) comes from a dense-stride scalar load,
//    fully L1-absorbed (same lines as the vector loads).
//  - Horizontal sums per lane yield output cols 2i, 2i+1, 128+2i, 128+2i+1
//    -> one wave produces a full 255-col output row.
//  - Vertical: rolling accumulator over a band of BAND output rows.
//    Invariant entering row m: A = h(2m). Loop: h1=h(2m+1), h2=h(2m+2),
//    store (A+h1+h2)/9, A=h2. Each input row is fetched exactly once per
//    wave; bands overlap by a single row (33 rows per 32 unique).
//  - Grid: 512 planes x 4 blocks x 4 waves = 16 bands/plane; 2048 blocks
//    = 8 blocks/CU = 32 waves/CU (max occupancy), ~30 VGPRs.

#define IN_H 512
#define IN_W 512
#define OUT_H 255
#define OUT_W 255
#define PLANES 512   // N*C = 8*64
#define BAND 16      // output rows per wave (last band: 15)

// rp = plane + ir*IN_W + 4*lane. Returns horizontal 3-sums for this lane's
// four output columns: {2i, 2i+1, 128+2i, 128+2i+1}.
__device__ __forceinline__ float4 hrow(const float* __restrict__ rp) {
    const float4 v0 = *(const float4*)(rp);         // cols 4i   .. 4i+3
    const float4 v1 = *(const float4*)(rp + 256);   // cols 256+4i .. 256+4i+3
    const float  n0 = rp[4];                        // col 4i+4   (L1 hit)
    const float  n1 = rp[260];                      // col 256+4i+4 (L1 hit;
                                                    // lane63: row+512 = next
                                                    // row col0, in-bounds,
                                                    // value never stored)
    float4 h;
    h.x = v0.x + v0.y + v0.z;   // out col 2i     : in 4i,4i+1,4i+2
    h.y = v0.z + v0.w + n0;     // out col 2i+1   : in 4i+2..4i+4
    h.z = v1.x + v1.y + v1.z;   // out col 128+2i : in 256+4i..+2
    h.w = v1.z + v1.w + n1;     // out col 129+2i : in 258+4i..+4
    return h;
}

__global__ __launch_bounds__(256) void KeyedAvgpool2d_kernel(
    const float* __restrict__ in, float* __restrict__ out) {
    const int lane = threadIdx.x & 63;
    const int wv   = threadIdx.x >> 6;
    const int band = blockIdx.x * 4 + wv;   // 0..15
    const int nc   = blockIdx.y;            // plane 0..511

    const int j0 = band * BAND;                       // first out row
    const int j1 = min(j0 + BAND, OUT_H);             // exclusive; band15 -> 15 rows

    const float* __restrict__ rp =
        in + (size_t)nc * (IN_H * IN_W) + (size_t)(2 * j0) * IN_W + 4 * lane;
    float* __restrict__ op =
        out + (size_t)nc * (OUT_H * OUT_W) + (size_t)j0 * OUT_W + 2 * lane;

    const float inv9 = 1.0f / 9.0f;

    float4 A = hrow(rp);                    // h(2*j0)
    for (int m = j0; m < j1; ++m) {
        rp += IN_W;
        const float4 h1 = hrow(rp);         // h(2m+1)
        rp += IN_W;
        const float4 h2 = hrow(rp);         // h(2m+2), max row 2*254+2 = 510
        op[0]   = (A.x + h1.x + h2.x) * inv9;   // out col 2i
        op[1]   = (A.y + h1.y + h2.y) * inv9;   // out col 2i+1
        op[128] = (A.z + h1.z + h2.z) * inv9;   // out col 128+2i
        if (lane < 63)                          // out col 255 doesn't exist
            op[129] = (A.w + h1.w + h2.w) * inv9;
        op += OUT_W;
        A = h2;                             // h(2(m+1)) for next out row
    }
}

extern "C" void kernel_launch(void* const* d_in, const int* in_sizes, int n_in,
                              void* d_out, int out_size, void* d_ws, size_t ws_size,
                              hipStream_t stream) {
    const float* x = (const float*)d_in[0];
    float* o = (float*)d_out;

    dim3 block(256, 1, 1);          // 4 waves = 4 bands
    dim3 grid(4, PLANES, 1);        // 4*4 = 16 bands ; 512 planes
    KeyedAvgpool2d_kernel<<<grid, block, 0, stream>>>(x, o);
}